// Round 2
// baseline (1681.243 us; speedup 1.0000x reference)
//
#include <hip/hip_runtime.h>
#include <hip/hip_bf16.h>
#include <cstdint>
#include <cstddef>

typedef unsigned short u16;

// ---------- constants ----------
#define BB   64      // batch
#define SS   24      // seq len
#define DD   300     // emb dim
#define DP   304     // padded emb dim (4-elem aligned rows)
#define NNODE 256
#define NEDGE 1024
#define HLS  512     // LSTM hidden
#define BNN  (BB*NNODE)   // 16384
#define BEE  (BB*NEDGE)   // 65536
#define OUTD 512
#define NAA  3000

// ---------- ws layout (bytes) ----------
static constexpr size_t O_COUNTS = 0;          // 16384*4
static constexpr size_t O_FILL   = 65536;      // 16384*4
static constexpr size_t O_ESUM   = 131072;     // 64*300*4
static constexpr size_t O_H0     = 207872;     // 64*512*4 (f32)
static constexpr size_t O_C      = 338944;     // 64*512*4
static constexpr size_t Z_BYTES  = 470016;     // zero span = all of the above
static constexpr size_t O_H1     = 470016;     // 64*512*4
static constexpr size_t O_XPROJ  = 601088;     // 1536*2048*4
static constexpr size_t O_NF     = 13184000;   // 16384*304*2 (bf16)
static constexpr size_t O_EF     = 23145472;   // 65536*304*2 (bf16)
static constexpr size_t O_HFEAT  = 62991360;   // 16384*512*2 (bf16)
static constexpr size_t O_RFEAT  = 79768576;   // 65536*512*2 (bf16)
static constexpr size_t O_SSRC   = 146877440;  // 16384*4*4
static constexpr size_t O_SDST   = 147139584;  // 16384*4*4
static constexpr size_t O_SE     = 147401728;  // 65536*4*4
static constexpr size_t O_SG     = 148450304;  // 65536*4
static constexpr size_t O_DG     = 148712448;  // 65536*4
static constexpr size_t O_RS     = 148974592;  // 16384*4
static constexpr size_t O_ELIST  = 149040128;  // 65536*4
static constexpr size_t O_LG     = 149302272;  // 65536*4*4 (logits -> alpha)
static constexpr size_t O_NOUT   = 150350848;  // 16384*512*2 (bf16)
static constexpr size_t O_NSUM   = 167128064;  // 64*512*4
static constexpr size_t O_QN     = 167259136;  // 64*512*4
static constexpr size_t O_QE     = 167390208;  // 64*300*4
static constexpr size_t O_QCAT   = 167467008;  // 64*1024*4
static constexpr size_t O_MID    = 167729152;  // 64*1536*4
// end = 168122368 (~168 MB)

// ---------- helpers ----------
__device__ __forceinline__ float bf(u16 u) {
  union { unsigned int i; float f; } c; c.i = ((unsigned int)u) << 16; return c.f;
}
__device__ __forceinline__ u16 f2bu(float f) {
  union { float f; unsigned int i; } c; c.f = f;
  unsigned int r = c.i + 0x7fffu + ((c.i >> 16) & 1u);
  return (u16)(r >> 16);
}

// ---------- trivial kernels ----------
__global__ __launch_bounds__(256) void k_zero(float* __restrict__ p, int n) {
  int i = blockIdx.x * 256 + threadIdx.x;
  int stride = gridDim.x * 256;
  for (; i < n; i += stride) p[i] = 0.f;
}

// node/edge phrase features: sum of 4 f32 embedding rows -> bf16, stride DP with zero pad
__global__ __launch_bounds__(256) void k_feat(const int* __restrict__ toks, const float* __restrict__ emb,
                                              u16* __restrict__ outp) {
  int r = blockIdx.x;
  int t0 = toks[r * 4 + 0], t1 = toks[r * 4 + 1], t2 = toks[r * 4 + 2], t3 = toks[r * 4 + 3];
  const size_t e0 = (size_t)t0 * DD, e1 = (size_t)t1 * DD, e2 = (size_t)t2 * DD, e3 = (size_t)t3 * DD;
  for (int c = threadIdx.x; c < DP; c += 256) {
    float v = 0.f;
    if (c < DD) v = emb[e0 + c] + emb[e1 + c] + emb[e2 + c] + emb[e3 + c];
    outp[(size_t)r * DP + c] = f2bu(v);
  }
}

// ---------- generic tiled GEMM: C[M,N] = A[M,K] @ W[K,N], f32 accum ----------
// A: bf16 (AT=u16) or f32 (AT=float), row stride lda, optional row gather.
// W: f32 row-major [K][N].
// mode 0: store bf16 Cb ; mode 2: store f32 Cf ;
// mode 1: relu then per-batch (1024 rows) column sums atomicAdd into bsum[b*N+col].
template <typename AT>
__global__ __launch_bounds__(256) void gemm_k(
    const AT* __restrict__ A, int lda, const int* __restrict__ rowmap,
    const float* __restrict__ W, int N, int K,
    u16* __restrict__ Cb, float* __restrict__ Cf, float* __restrict__ bsum, int mode) {
  __shared__ float As[32][128];   // [k][r]
  __shared__ float Ws[32][128];   // [k][n]
  int tid = threadIdx.x;
  int tx = tid & 15, ty = tid >> 4;
  int row0 = blockIdx.y * 128, col0 = blockIdx.x * 128;

  float acc[8][8];
#pragma unroll
  for (int i = 0; i < 8; ++i)
#pragma unroll
    for (int j = 0; j < 8; ++j) acc[i][j] = 0.f;

  for (int k0 = 0; k0 < K; k0 += 32) {
    // stage A tile: 128 rows x 32 k (1024 4-elem segments)
    for (int s = tid; s < 1024; s += 256) {
      int r = s >> 3;
      int kc = (s & 7) << 2;
      int kk = k0 + kc;
      float f0 = 0.f, f1 = 0.f, f2 = 0.f, f3 = 0.f;
      if (kk + 3 < lda) {
        int ar = row0 + r;
        if (rowmap) ar = rowmap[ar];
        if constexpr (sizeof(AT) == 2) {
          ushort4 v = *reinterpret_cast<const ushort4*>(&A[(size_t)ar * lda + kk]);
          f0 = bf(v.x); f1 = bf(v.y); f2 = bf(v.z); f3 = bf(v.w);
        } else {
          float4 v = *reinterpret_cast<const float4*>(&A[(size_t)ar * lda + kk]);
          f0 = v.x; f1 = v.y; f2 = v.z; f3 = v.w;
        }
      }
      As[kc + 0][r] = f0; As[kc + 1][r] = f1; As[kc + 2][r] = f2; As[kc + 3][r] = f3;
    }
    // stage W tile: 32 k x 128 n
    for (int s = tid; s < 1024; s += 256) {
      int kr = s >> 5;
      int nc = (s & 31) << 2;
      int kk = k0 + kr;
      int col = col0 + nc;
      float4 wv; wv.x = 0.f; wv.y = 0.f; wv.z = 0.f; wv.w = 0.f;
      if (kk < K) {
        if (col + 3 < N) {
          wv = *reinterpret_cast<const float4*>(&W[(size_t)kk * N + col]);
        } else if (col < N) {
          wv.x = W[(size_t)kk * N + col];
          if (col + 1 < N) wv.y = W[(size_t)kk * N + col + 1];
          if (col + 2 < N) wv.z = W[(size_t)kk * N + col + 2];
        }
      }
      *reinterpret_cast<float4*>(&Ws[kr][nc]) = wv;
    }
    __syncthreads();
#pragma unroll 8
    for (int k = 0; k < 32; ++k) {
      float a[8], b[8];
      *reinterpret_cast<float4*>(&a[0]) = *reinterpret_cast<float4*>(&As[k][ty * 8]);
      *reinterpret_cast<float4*>(&a[4]) = *reinterpret_cast<float4*>(&As[k][ty * 8 + 4]);
      *reinterpret_cast<float4*>(&b[0]) = *reinterpret_cast<float4*>(&Ws[k][tx * 8]);
      *reinterpret_cast<float4*>(&b[4]) = *reinterpret_cast<float4*>(&Ws[k][tx * 8 + 4]);
#pragma unroll
      for (int i = 0; i < 8; ++i)
#pragma unroll
        for (int j = 0; j < 8; ++j) acc[i][j] = fmaf(a[i], b[j], acc[i][j]);
    }
    __syncthreads();
  }

  if (mode == 0) {
#pragma unroll
    for (int i = 0; i < 8; ++i) {
      int gr = row0 + ty * 8 + i;
#pragma unroll
      for (int j = 0; j < 8; ++j) {
        int gc = col0 + tx * 8 + j;
        if (gc < N) Cb[(size_t)gr * N + gc] = f2bu(acc[i][j]);
      }
    }
  } else if (mode == 2) {
#pragma unroll
    for (int i = 0; i < 8; ++i) {
      int gr = row0 + ty * 8 + i;
#pragma unroll
      for (int j = 0; j < 8; ++j) {
        int gc = col0 + tx * 8 + j;
        if (gc < N) Cf[(size_t)gr * N + gc] = acc[i][j];
      }
    }
  } else {
    // mode 1: relu + per-batch column sum
    float cs[8];
#pragma unroll
    for (int j = 0; j < 8; ++j) {
      float s = 0.f;
#pragma unroll
      for (int i = 0; i < 8; ++i) s += fmaxf(acc[i][j], 0.f);
      cs[j] = s;
    }
    float* red = &As[0][0];  // reuse 16x128
    __syncthreads();
#pragma unroll
    for (int j = 0; j < 8; ++j) red[ty * 128 + tx * 8 + j] = cs[j];
    __syncthreads();
    if (tid < 128) {
      float s = 0.f;
      for (int y = 0; y < 16; ++y) s += red[y * 128 + tid];
      int gc = col0 + tid;
      if (gc < N) atomicAdd(&bsum[(size_t)(row0 >> 10) * N + gc], s);
    }
  }
}

// ---------- LSTM step ----------
__global__ __launch_bounds__(256) void k_lstm(
    const float* __restrict__ whh, const float* __restrict__ xproj,
    const float* __restrict__ bls, const int* __restrict__ qmask,
    const float* __restrict__ h_in, float* __restrict__ h_out, float* __restrict__ c, int t) {
  __shared__ float hs[4][512];
  int tid = threadIdx.x;
  int j = (blockIdx.x << 6) + (tid & 63);   // 0..511
  int bq = tid >> 6;                        // 0..3
  int b = (blockIdx.y << 2) + bq;
  for (int i = tid; i < 2048; i += 256)
    hs[i >> 9][i & 511] = h_in[(size_t)((blockIdx.y << 2) + (i >> 9)) * 512 + (i & 511)];
  __syncthreads();
  float a0 = 0.f, a1 = 0.f, a2 = 0.f, a3 = 0.f;
#pragma unroll 8
  for (int k = 0; k < 512; ++k) {
    float hv = hs[bq][k];
    const float* w = whh + (size_t)k * 2048 + j;
    a0 = fmaf(hv, w[0], a0);
    a1 = fmaf(hv, w[512], a1);
    a2 = fmaf(hv, w[1024], a2);
    a3 = fmaf(hv, w[1536], a3);
  }
  size_t xb = ((size_t)b * SS + t) * 2048;
  float gi = a0 + xproj[xb + j] + bls[j];
  float gf = a1 + xproj[xb + 512 + j] + bls[512 + j];
  float gg = a2 + xproj[xb + 1024 + j] + bls[1024 + j];
  float go = a3 + xproj[xb + 1536 + j] + bls[1536 + j];
  float si = 1.f / (1.f + __expf(-gi));
  float sf = 1.f / (1.f + __expf(-gf));
  float so = 1.f / (1.f + __expf(-go));
  float tg = 2.f / (1.f + __expf(-2.f * gg)) - 1.f;
  int idx = b * 512 + j;
  float cold = c[idx];
  float cn = sf * cold + si * tg;
  float hn = so * (2.f / (1.f + __expf(-2.f * cn)) - 1.f);
  if (qmask[b * SS + t] > 0) { c[idx] = cn; h_out[idx] = hn; }
  else h_out[idx] = h_in[idx];
}

// ---------- GAT score kernels ----------
__global__ __launch_bounds__(256) void k_snode(const u16* __restrict__ hfeat,
    const float* __restrict__ a_src, const float* __restrict__ a_dst,
    float* __restrict__ ssrc, float* __restrict__ sdst) {
  __shared__ float as[4 * 132], ad[4 * 132];
  int tid = threadIdx.x;
  for (int i = tid; i < 512; i += 256) {
    int h = i >> 7, d = i & 127;
    as[h * 132 + d] = a_src[i];
    ad[h * 132 + d] = a_dst[i];
  }
  __syncthreads();
  int id = blockIdx.x * 256 + tid;  // < 65536
  int n = id >> 2, h = id & 3;
  const u16* hp = hfeat + (size_t)n * 512 + h * 128;
  float s1 = 0.f, s2 = 0.f;
  for (int d = 0; d < 128; d += 4) {
    ushort4 v = *reinterpret_cast<const ushort4*>(&hp[d]);
    float f0 = bf(v.x), f1 = bf(v.y), f2 = bf(v.z), f3 = bf(v.w);
    int o = h * 132 + d;
    s1 += f0 * as[o] + f1 * as[o + 1] + f2 * as[o + 2] + f3 * as[o + 3];
    s2 += f0 * ad[o] + f1 * ad[o + 1] + f2 * ad[o + 2] + f3 * ad[o + 3];
  }
  ssrc[id] = s1; sdst[id] = s2;
}

__global__ __launch_bounds__(256) void k_sedge(const u16* __restrict__ rfeat,
    const float* __restrict__ a_edge, float* __restrict__ se) {
  __shared__ float ae[4 * 132];
  int tid = threadIdx.x;
  for (int i = tid; i < 512; i += 256) { int h = i >> 7, d = i & 127; ae[h * 132 + d] = a_edge[i]; }
  __syncthreads();
  int id = blockIdx.x * 256 + tid;  // < 262144
  int e = id >> 2, h = id & 3;
  const u16* rp = rfeat + (size_t)e * 512 + h * 128;
  float s = 0.f;
  for (int d = 0; d < 128; d += 4) {
    ushort4 v = *reinterpret_cast<const ushort4*>(&rp[d]);
    int o = h * 132 + d;
    s += bf(v.x) * ae[o] + bf(v.y) * ae[o + 1] + bf(v.z) * ae[o + 2] + bf(v.w) * ae[o + 3];
  }
  se[id] = s;
}

// ---------- CSR build ----------
__global__ __launch_bounds__(256) void k_prep(const int* __restrict__ src, const int* __restrict__ dst,
    int* __restrict__ sg, int* __restrict__ dg, int* __restrict__ counts) {
  int i = blockIdx.x * 256 + threadIdx.x;  // < 65536
  int b = i >> 10;
  sg[i] = (b << 8) + src[i];
  int dgl = (b << 8) + dst[i];
  dg[i] = dgl;
  atomicAdd(&counts[dgl], 1);
}

__global__ __launch_bounds__(256) void k_scan(const int* __restrict__ counts, int* __restrict__ rs) {
  __shared__ int sc[256];
  int b = blockIdx.x, tid = threadIdx.x;
  int v = counts[b * 256 + tid];
  sc[tid] = v;
  __syncthreads();
  for (int off = 1; off < 256; off <<= 1) {
    int add = (tid >= off) ? sc[tid - off] : 0;
    __syncthreads();
    sc[tid] += add;
    __syncthreads();
  }
  rs[b * 256 + tid] = b * 1024 + sc[tid] - v;
}

__global__ __launch_bounds__(256) void k_scatter(const int* __restrict__ dg, const int* __restrict__ rs,
    int* __restrict__ fill, int* __restrict__ elist) {
  int i = blockIdx.x * 256 + threadIdx.x;
  int d = dg[i];
  int pos = rs[d] + atomicAdd(&fill[d], 1);
  elist[pos] = i;
}

// ---------- logits / softmax / aggregate ----------
__global__ __launch_bounds__(256) void k_logit(const int* __restrict__ sg, const int* __restrict__ dg,
    const float* __restrict__ ssrc, const float* __restrict__ sdst,
    const float* __restrict__ se, float* __restrict__ lg) {
  int i = blockIdx.x * 256 + threadIdx.x;  // < 262144
  int e = i >> 2, h = i & 3;
  float x = ssrc[sg[e] * 4 + h] + sdst[dg[e] * 4 + h] + se[i];
  lg[i] = x > 0.f ? x : 0.2f * x;
}

__global__ __launch_bounds__(256) void k_soft(const int* __restrict__ counts, const int* __restrict__ rs,
    const int* __restrict__ elist, float* __restrict__ lg) {
  int id = blockIdx.x * 256 + threadIdx.x;  // < 65536
  int n = id >> 2, h = id & 3;
  int deg = counts[n];
  if (deg == 0) return;
  int st = rs[n];
  float m = -1e30f;
  for (int i = 0; i < deg; ++i) { int e = elist[st + i]; m = fmaxf(m, lg[e * 4 + h]); }
  float s = 0.f;
  for (int i = 0; i < deg; ++i) {
    int e = elist[st + i];
    float p = __expf(lg[e * 4 + h] - m);
    lg[e * 4 + h] = p;
    s += p;
  }
  float inv = 1.f / (s + 1e-9f);
  for (int i = 0; i < deg; ++i) { int e = elist[st + i]; lg[e * 4 + h] *= inv; }
}

__global__ __launch_bounds__(256) void k_agg(const int* __restrict__ counts, const int* __restrict__ rs,
    const int* __restrict__ elist, const int* __restrict__ sg, const float* __restrict__ lg,
    const u16* __restrict__ hfeat, const u16* __restrict__ rfeat, u16* __restrict__ nout) {
  int n = blockIdx.x;
  int deg = counts[n], st = rs[n];
  int c1 = threadIdx.x, c2 = threadIdx.x + 256;
  float a1 = 0.f, a2 = 0.f;
  for (int i = 0; i < deg; ++i) {
    int e = elist[st + i];
    int s = sg[e];
    float al1 = lg[e * 4 + (c1 >> 7)], al2 = lg[e * 4 + (c2 >> 7)];
    a1 += al1 * (bf(hfeat[(size_t)s * 512 + c1]) + bf(rfeat[(size_t)e * 512 + c1]));
    a2 += al2 * (bf(hfeat[(size_t)s * 512 + c2]) + bf(rfeat[(size_t)e * 512 + c2]));
  }
  a1 = a1 > 0.f ? a1 : __expf(a1) - 1.f;  // elu
  a2 = a2 > 0.f ? a2 : __expf(a2) - 1.f;
  nout[(size_t)n * 512 + c1] = f2bu(a1);
  nout[(size_t)n * 512 + c2] = f2bu(a2);
}

__global__ __launch_bounds__(512) void k_nodesum(const u16* __restrict__ nout, float* __restrict__ nsum) {
  int b = blockIdx.x, col = threadIdx.x;
  float s = 0.f;
  for (int n = 0; n < 256; ++n) s += bf(nout[(size_t)((b << 8) + n) * 512 + col]);
  nsum[b * 512 + col] = s;
}

// ---------- fusion head ----------
__global__ __launch_bounds__(256) void k_fin1(const float* __restrict__ hq,
    const float* __restrict__ Wqn, const float* __restrict__ bqn,
    const float* __restrict__ Wqe, const float* __restrict__ bqe,
    const float* __restrict__ nsum, const float* __restrict__ esum,
    float* __restrict__ qn, float* __restrict__ qe) {
  __shared__ float h[512];
  int b = blockIdx.y, tid = threadIdx.x;
  for (int i = tid; i < 512; i += 256) h[i] = hq[b * 512 + i];
  __syncthreads();
  int idx = blockIdx.x * 256 + tid;
  if (idx < 512) {
    float s = 0.f;
    for (int k = 0; k < 512; ++k) s = fmaf(h[k], Wqn[(size_t)k * 512 + idx], s);
    qn[b * 512 + idx] = s + bqn[idx] + nsum[b * 512 + idx];
  } else if (idx < 812) {
    int cc = idx - 512;
    float s = 0.f;
    for (int k = 0; k < 512; ++k) s = fmaf(h[k], Wqe[(size_t)k * 300 + cc], s);
    qe[b * 300 + cc] = s + bqe[cc] + esum[b * 300 + cc];
  }
}

__global__ __launch_bounds__(256) void k_fin2(const float* __restrict__ qe, const float* __restrict__ qn,
    const float* __restrict__ Wep, const float* __restrict__ bep, float* __restrict__ qcat) {
  __shared__ float q[300];
  int b = blockIdx.y, tid = threadIdx.x;
  for (int i = tid; i < 300; i += 256) q[i] = qe[b * 300 + i];
  __syncthreads();
  int idx = blockIdx.x * 256 + tid;  // < 512
  float s = 0.f;
  for (int k = 0; k < 300; ++k) s = fmaf(q[k], Wep[(size_t)k * 512 + idx], s);
  qcat[b * 1024 + idx] = s + bep[idx];
  qcat[b * 1024 + 512 + idx] = qn[b * 512 + idx];
}

__global__ __launch_bounds__(256) void k_mid(const float* __restrict__ qcat,
    const float* __restrict__ Wm, const float* __restrict__ bm, float* __restrict__ mid) {
  __shared__ float q[1024];
  int b = blockIdx.y, tid = threadIdx.x;
  for (int i = tid; i < 1024; i += 256) q[i] = qcat[b * 1024 + i];
  __syncthreads();
  int idx = blockIdx.x * 256 + tid;  // < 1536
  float s = 0.f;
  for (int k = 0; k < 1024; ++k) s = fmaf(q[k], Wm[(size_t)k * 1536 + idx], s);
  mid[b * 1536 + idx] = s + bm[idx];
}

__global__ __launch_bounds__(256) void k_outp(const float* __restrict__ mid,
    const float* __restrict__ Wp, const float* __restrict__ bp, float* __restrict__ outp) {
  __shared__ float ms[2][1536];
  int b0 = blockIdx.x * 2, tid = threadIdx.x;
  for (int i = tid; i < 3072; i += 256) {
    int r = i / 1536, k = i - r * 1536;
    ms[r][k] = mid[(size_t)(b0 + r) * 1536 + k];
  }
  __syncthreads();
  int col = blockIdx.y * 256 + tid;
  if (col >= NAA) return;
  float a0 = 0.f, a1 = 0.f;
  for (int k = 0; k < 1536; ++k) {
    float w = Wp[(size_t)k * NAA + col];
    a0 = fmaf(ms[0][k], w, a0);
    a1 = fmaf(ms[1][k], w, a1);
  }
  float bb = bp[col];
  outp[(size_t)b0 * NAA + col] = a0 + bb;
  outp[(size_t)(b0 + 1) * NAA + col] = a1 + bb;
}

// ---------- launch ----------
extern "C" void kernel_launch(void* const* d_in, const int* in_sizes, int n_in,
                              void* d_out, int out_size, void* d_ws, size_t ws_size,
                              hipStream_t stream) {
  const int*   question   = (const int*)d_in[0];
  const int*   qmask      = (const int*)d_in[1];
  const int*   node_toks  = (const int*)d_in[2];
  const int*   edge_toks  = (const int*)d_in[3];
  const int*   src_ids    = (const int*)d_in[4];
  const int*   dst_ids    = (const int*)d_in[5];
  const float* word_emb   = (const float*)d_in[6];
  const float* W_ih       = (const float*)d_in[7];
  const float* W_hh       = (const float*)d_in[8];
  const float* b_lstm     = (const float*)d_in[9];
  const float* W_node     = (const float*)d_in[10];
  const float* W_rel      = (const float*)d_in[11];
  const float* a_src      = (const float*)d_in[12];
  const float* a_dst      = (const float*)d_in[13];
  const float* a_edge     = (const float*)d_in[14];
  const float* W_edge_upd = (const float*)d_in[15];
  const float* W_qnode    = (const float*)d_in[16];
  const float* b_qnode    = (const float*)d_in[17];
  const float* W_qedge    = (const float*)d_in[18];
  const float* b_qedge    = (const float*)d_in[19];
  const float* W_edge_prj = (const float*)d_in[20];
  const float* b_edge_prj = (const float*)d_in[21];
  const float* W_mid      = (const float*)d_in[22];
  const float* b_mid      = (const float*)d_in[23];
  const float* W_pre      = (const float*)d_in[24];
  const float* b_pre      = (const float*)d_in[25];
  float* outp = (float*)d_out;

  char* ws = (char*)d_ws;
  int*   counts = (int*)(ws + O_COUNTS);
  int*   fill   = (int*)(ws + O_FILL);
  float* esum   = (float*)(ws + O_ESUM);
  float* h0     = (float*)(ws + O_H0);
  float* cst    = (float*)(ws + O_C);
  float* h1     = (float*)(ws + O_H1);
  float* xproj  = (float*)(ws + O_XPROJ);
  u16*   nf     = (u16*)(ws + O_NF);
  u16*   ef     = (u16*)(ws + O_EF);
  u16*   hfeat  = (u16*)(ws + O_HFEAT);
  u16*   rfeat  = (u16*)(ws + O_RFEAT);
  float* ssrc   = (float*)(ws + O_SSRC);
  float* sdst   = (float*)(ws + O_SDST);
  float* se     = (float*)(ws + O_SE);
  int*   sg     = (int*)(ws + O_SG);
  int*   dg     = (int*)(ws + O_DG);
  int*   rs     = (int*)(ws + O_RS);
  int*   elist  = (int*)(ws + O_ELIST);
  float* lg     = (float*)(ws + O_LG);
  u16*   nout   = (u16*)(ws + O_NOUT);
  float* nsum   = (float*)(ws + O_NSUM);
  float* qn     = (float*)(ws + O_QN);
  float* qe     = (float*)(ws + O_QE);
  float* qcat   = (float*)(ws + O_QCAT);
  float* midb   = (float*)(ws + O_MID);

  // 1. zero accumulator span (counts/fill/esum/h0/c)
  k_zero<<<128, 256, 0, stream>>>((float*)ws, (int)(Z_BYTES / 4));
  // 2. node/edge phrase features (f32 emb -> bf16, padded)
  k_feat<<<BNN, 256, 0, stream>>>(node_toks, word_emb, nf);
  k_feat<<<BEE, 256, 0, stream>>>(edge_toks, word_emb, ef);
  // 3. xproj = emb(question) @ W_ih  (f32 A with row gather)
  gemm_k<float><<<dim3(16, 12), 256, 0, stream>>>(word_emb, DD, question, W_ih, 2048, DD,
                                                  nullptr, xproj, nullptr, 2);
  // 4. LSTM: 24 steps, ping-pong h (final lands in h0: t=23 odd writes h0)
  for (int t = 0; t < SS; ++t) {
    const float* hin = (t & 1) ? h1 : h0;
    float* hout = (t & 1) ? h0 : h1;
    k_lstm<<<dim3(8, 16), 256, 0, stream>>>(W_hh, xproj, b_lstm, qmask, hin, hout, cst, t);
  }
  // 5. big GEMMs (bf16 A, f32 W)
  gemm_k<u16><<<dim3(4, 128), 256, 0, stream>>>(nf, DP, nullptr, W_node, 512, DD, hfeat, nullptr, nullptr, 0);
  gemm_k<u16><<<dim3(4, 512), 256, 0, stream>>>(ef, DP, nullptr, W_rel, 512, DD, rfeat, nullptr, nullptr, 0);
  gemm_k<u16><<<dim3(3, 512), 256, 0, stream>>>(ef, DP, nullptr, W_edge_upd, 300, DD, nullptr, nullptr, esum, 1);
  // 6. GAT scores
  k_snode<<<256, 256, 0, stream>>>(hfeat, a_src, a_dst, ssrc, sdst);
  k_sedge<<<1024, 256, 0, stream>>>(rfeat, a_edge, se);
  // 7. CSR by dst
  k_prep<<<256, 256, 0, stream>>>(src_ids, dst_ids, sg, dg, counts);
  k_scan<<<64, 256, 0, stream>>>(counts, rs);
  k_scatter<<<256, 256, 0, stream>>>(dg, rs, fill, elist);
  // 8. logits -> softmax -> aggregate
  k_logit<<<1024, 256, 0, stream>>>(sg, dg, ssrc, sdst, se, lg);
  k_soft<<<256, 256, 0, stream>>>(counts, rs, elist, lg);
  k_agg<<<BNN, 256, 0, stream>>>(counts, rs, elist, sg, lg, hfeat, rfeat, nout);
  k_nodesum<<<64, 512, 0, stream>>>(nout, nsum);
  // 9. fusion head
  k_fin1<<<dim3(4, 64), 256, 0, stream>>>(h0, W_qnode, b_qnode, W_qedge, b_qedge, nsum, esum, qn, qe);
  k_fin2<<<dim3(2, 64), 256, 0, stream>>>(qe, qn, W_edge_prj, b_edge_prj, qcat);
  k_mid<<<dim3(6, 64), 256, 0, stream>>>(qcat, W_mid, b_mid, midb);
  k_outp<<<dim3(32, 12), 256, 0, stream>>>(midb, W_pre, b_pre, outp);
}